// Round 7
// baseline (279.560 us; speedup 1.0000x reference)
//
#include <hip/hip_runtime.h>
#include <hip/hip_bf16.h>

// ---------------------------------------------------------------------------
// GCN 3-layer, N=50000, E=800000, D=64, fp32 in/out.
// R7: agg gather rework — uint4 payload (16 B/lane, 8 lanes/row, 8 nodes/
// wave: half the vmem instrs of R6), adjacency indices via one coalesced
// 32 B load + __shfl fan-out (kills 8x same-address broadcast loads), and
// nontemporal hints on the streaming res/h/out traffic so the 6.4 MB bf16
// gather table stays L2-resident. Split structure from R4 (fused R5 choked
// occupancy); bf16 table from R6 (absmax 0.0078 < 0.035).
// ---------------------------------------------------------------------------

#define CAP 64
#define EDGE_CHUNK 1024

typedef float f4v __attribute__((ext_vector_type(4)));

// --- pack two fp32 -> bf16x2 (RNE) ----------------------------------------
__device__ inline unsigned pack_bf16(float a, float b) {
    union { float f; unsigned i; } ua, ub;
    ua.f = a; ub.f = b;
    unsigned x = (ua.i + 0x7fffu + ((ua.i >> 16) & 1u)) >> 16;
    unsigned y = (ub.i + 0x7fffu + ((ub.i >> 16) & 1u)) >> 16;
    return x | (y << 16);
}
// --- accumulate bf16x2 (packed uint) into two floats ----------------------
__device__ inline void acc_bf16x2(unsigned u, float& a, float& b) {
    union { unsigned i; float f; } lo, hi;
    lo.i = u << 16;
    hi.i = u & 0xffff0000u;
    a += lo.f; b += hi.f;
}

// --- fused count+place: slot = atomicAdd(cnt), XCD-partitioned by dst -----
__global__ void fill_kernel(const int* __restrict__ src, const int* __restrict__ dst,
                            int* __restrict__ cnt, int* __restrict__ adj,
                            int E, int npc) {
    int cls = blockIdx.x & 7;          // -> XCD (round-robin heuristic)
    int base = (blockIdx.x >> 3) * EDGE_CHUNK;
    int end = min(base + EDGE_CHUNK, E);
    int lo = cls * npc, hi = lo + npc;
    for (int e = base + threadIdx.x; e < end; e += blockDim.x) {
        int d = dst[e];
        if (d >= lo && d < hi) {
            int p = atomicAdd(&cnt[d], 1);
            adj[(size_t)d * CAP + p] = src[e];
        }
    }
}

// --- g(bf16) = dinv ⊙ (in @ W); 32x64 tile / 256 threads, 2x4/thread ------
__global__ __launch_bounds__(256) void gemm_kernel(const float* __restrict__ in,
                                                   const float* __restrict__ W,
                                                   const int* __restrict__ cnt,
                                                   unsigned short* __restrict__ g, int n) {
    __shared__ float xsT[64][34];   // [k][row], pad->34
    __shared__ float Ws[64][64];
    int t = threadIdx.x;
    int r0 = blockIdx.x * 32;

    {
        const float4* W4 = (const float4*)W;
        float4* Ws4 = (float4*)&Ws[0][0];
#pragma unroll
        for (int i = 0; i < 4; i++) Ws4[t + i * 256] = W4[t + i * 256];
    }
    {
        int rr = t >> 4;
        int cc = (t & 15) * 4;
#pragma unroll
        for (int p = 0; p < 2; p++) {
            int rl = p * 16 + rr;
            int r = r0 + rl;
            float4 v = make_float4(0.f, 0.f, 0.f, 0.f);
            if (r < n) v = *(const float4*)&in[(size_t)r * 64 + cc];
            xsT[cc + 0][rl] = v.x;
            xsT[cc + 1][rl] = v.y;
            xsT[cc + 2][rl] = v.z;
            xsT[cc + 3][rl] = v.w;
        }
    }
    __syncthreads();

    int cgrp = t & 15;   // cols cgrp*4..+3
    int rgrp = t >> 4;   // rows rgrp*2..+1
    float4 acc0 = make_float4(0, 0, 0, 0), acc1 = acc0;
#pragma unroll
    for (int k = 0; k < 64; k++) {
        float2 a = *(const float2*)&xsT[k][rgrp * 2];
        float4 b = *(const float4*)&Ws[k][cgrp * 4];
        acc0.x += a.x * b.x; acc0.y += a.x * b.y; acc0.z += a.x * b.z; acc0.w += a.x * b.w;
        acc1.x += a.y * b.x; acc1.y += a.y * b.y; acc1.z += a.y * b.z; acc1.w += a.y * b.w;
    }
    float4 accs[2] = {acc0, acc1};
    int rbase = r0 + rgrp * 2;
#pragma unroll
    for (int i = 0; i < 2; i++) {
        int r = rbase + i;
        if (r < n) {
            float d = rsqrtf((float)(cnt[r] + 1));
            float4 o = accs[i];
            uint2 pk;
            pk.x = pack_bf16(o.x * d, o.y * d);
            pk.y = pack_bf16(o.z * d, o.w * d);
            *(uint2*)&g[(size_t)r * 64 + cgrp * 4] = pk;
        }
    }
}

// --- aggregation: 8 lanes/node (uint4 = 8 bf16 /lane), 8 nodes/wave -------
// adjacency: lane lg loads lst[k+lg] (coalesced), fan-out via __shfl.
// out[i] = dinv[i]*(g[i] + sum_nbr g[j]) + bias  (+relu+res for MODE 0)
template <int MODE>
__global__ __launch_bounds__(256) void agg_kernel(const unsigned short* __restrict__ g,
                                                  const int* __restrict__ cnt,
                                                  const int* __restrict__ adj,
                                                  const float* __restrict__ bias,
                                                  const float* __restrict__ res,
                                                  float* __restrict__ out, int n) {
    int t = threadIdx.x;
    int lg = t & 7;                   // lane within 8-lane node group
    int i = blockIdx.x * 32 + (t >> 3);
    if (i >= n) return;
    int gbase = (t & 63) & ~7;        // group base lane within wave
    int deg = cnt[i];
    const int* lst = adj + (size_t)i * CAP;
    const int c8 = lg * 8;            // bf16 feature offset (16 B)
    float a0, a1, a2, a3, a4, a5, a6, a7;
    {   // self loop
        uint4 v = *(const uint4*)&g[(size_t)i * 64 + c8];
        a0 = a1 = a2 = a3 = a4 = a5 = a6 = a7 = 0.f;
        acc_bf16x2(v.x, a0, a1); acc_bf16x2(v.y, a2, a3);
        acc_bf16x2(v.z, a4, a5); acc_bf16x2(v.w, a6, a7);
    }
    int k = 0;
    for (; k + 8 <= deg; k += 8) {    // full chunks: no per-q predication
        int jv = lst[k + lg];         // one 32 B coalesced load per group
#pragma unroll
        for (int q = 0; q < 8; q++) {
            int j = __shfl(jv, gbase + q);
            uint4 v = *(const uint4*)&g[(size_t)j * 64 + c8];
            acc_bf16x2(v.x, a0, a1); acc_bf16x2(v.y, a2, a3);
            acc_bf16x2(v.z, a4, a5); acc_bf16x2(v.w, a6, a7);
        }
    }
    if (k < deg) {                    // tail (reads ≤7 slots past deg: CAP=64)
        int jv = lst[k + lg];
        int m = deg - k;
#pragma unroll
        for (int q = 0; q < 8; q++) {
            if (q < m) {
                int j = __shfl(jv, gbase + q);
                uint4 v = *(const uint4*)&g[(size_t)j * 64 + c8];
                acc_bf16x2(v.x, a0, a1); acc_bf16x2(v.y, a2, a3);
                acc_bf16x2(v.z, a4, a5); acc_bf16x2(v.w, a6, a7);
            }
        }
    }
    float dv = rsqrtf((float)(deg + 1));
    const float* bp = &bias[c8];
    float4 b0 = *(const float4*)&bp[0];
    float4 b1 = *(const float4*)&bp[4];
    f4v o0, o1;
    o0.x = dv * a0 + b0.x; o0.y = dv * a1 + b0.y;
    o0.z = dv * a2 + b0.z; o0.w = dv * a3 + b0.w;
    o1.x = dv * a4 + b1.x; o1.y = dv * a5 + b1.y;
    o1.z = dv * a6 + b1.z; o1.w = dv * a7 + b1.w;
    size_t rowoff = (size_t)i * 64 + c8;
    if (MODE == 0) {
        // streaming residual: nontemporal (keep g table L2-resident)
        f4v r0 = __builtin_nontemporal_load((const f4v*)&res[rowoff]);
        f4v r1 = __builtin_nontemporal_load((const f4v*)&res[rowoff + 4]);
        o0.x = fmaxf(o0.x, 0.f) + r0.x; o0.y = fmaxf(o0.y, 0.f) + r0.y;
        o0.z = fmaxf(o0.z, 0.f) + r0.z; o0.w = fmaxf(o0.w, 0.f) + r0.w;
        o1.x = fmaxf(o1.x, 0.f) + r1.x; o1.y = fmaxf(o1.y, 0.f) + r1.y;
        o1.z = fmaxf(o1.z, 0.f) + r1.z; o1.w = fmaxf(o1.w, 0.f) + r1.w;
    }
    __builtin_nontemporal_store(o0, (f4v*)&out[rowoff]);
    __builtin_nontemporal_store(o1, (f4v*)&out[rowoff + 4]);
}

extern "C" void kernel_launch(void* const* d_in, const int* in_sizes, int n_in,
                              void* d_out, int out_size, void* d_ws, size_t ws_size,
                              hipStream_t stream) {
    const float* x  = (const float*)d_in[0];
    const int*   ei = (const int*)d_in[1];
    const float* W1 = (const float*)d_in[2];
    const float* b1 = (const float*)d_in[3];
    const float* W2 = (const float*)d_in[4];
    const float* b2 = (const float*)d_in[5];
    const float* W3 = (const float*)d_in[6];
    const float* b3 = (const float*)d_in[7];
    float* out = (float*)d_out;

    const int N = in_sizes[0] / 64;
    const int E = in_sizes[1] / 2;
    const int* src = ei;
    const int* dst = ei + E;
    const int npc = (N + 7) / 8;
    const int nEdgeChunks = (E + EDGE_CHUNK - 1) / EDGE_CHUNK;

    // workspace layout
    char* p = (char*)d_ws;
    int*            cnt = (int*)p;            p += ((N + 63) / 64) * 64 * 4;
    int*            adj = (int*)p;            p += ((size_t)N + 1) * CAP * 4;  // +1 row tail pad
    unsigned short* g   = (unsigned short*)p; p += (size_t)N * 64 * 2;
    float*          h   = (float*)p;          p += (size_t)N * 64 * 4;

    const int aggBlocks  = (N + 31) / 32;
    const int gemmBlocks = (N + 31) / 32;

    // --- bucket adjacency build (ws re-poisoned every call) ---
    hipMemsetAsync(cnt, 0, (size_t)N * 4, stream);
    fill_kernel<<<nEdgeChunks * 8, 256, 0, stream>>>(src, dst, cnt, adj, E, npc);

    // --- layer 1: h = relu(agg(dinv⊙(x@W1))) + x ---
    gemm_kernel<<<gemmBlocks, 256, 0, stream>>>(x, W1, cnt, g, N);
    agg_kernel<0><<<aggBlocks, 256, 0, stream>>>(g, cnt, adj, b1, x, h, N);

    // --- layer 2: h = relu(agg(dinv⊙(h@W2))) + h ---
    gemm_kernel<<<gemmBlocks, 256, 0, stream>>>(h, W2, cnt, g, N);
    agg_kernel<0><<<aggBlocks, 256, 0, stream>>>(g, cnt, adj, b2, h, h, N);

    // --- layer 3: out = agg(dinv⊙(h@W3)) ---
    gemm_kernel<<<gemmBlocks, 256, 0, stream>>>(h, W3, cnt, g, N);
    agg_kernel<1><<<aggBlocks, 256, 0, stream>>>(g, cnt, adj, b3, nullptr, out, N);
}

// Round 8
// 198.650 us; speedup vs baseline: 1.4073x; 1.4073x over previous
//
#include <hip/hip_runtime.h>
#include <hip/hip_bf16.h>

// ---------------------------------------------------------------------------
// GCN 3-layer, N=50000, E=800000, D=64, fp32 in/out.
// R8: the fp32 vector GEMM was 45 us/layer (LDS-pipe + v_fma issue bound,
// 393 KB LDS traffic per block). Replaced with MFMA 16x16x32_bf16: W staged
// per-block in B-fragment order (8 KB LDS, conflict-free ds_read_b128),
// A-frags cvt'd fp32->bf16 in registers, 8 MFMAs per wave for a 16x64 slab.
// Agg reverted to R6's measured-best form (R7 shfl/NT rework regressed).
// Layouts per cdna_hip_programming.md §3 (m89/m91-verified):
//   A[m=lane&15][k=quad*8+j] ; B[k=quad*8+j][n=lane&15] ;
//   C/D: col=lane&15, row=quad*4+reg.
// ---------------------------------------------------------------------------

#define CAP 64
#define EDGE_CHUNK 1024

typedef __attribute__((ext_vector_type(8))) short bf16x8;
typedef __attribute__((ext_vector_type(4))) float f32x4;

// --- pack two fp32 -> bf16x2 (RNE) ----------------------------------------
__device__ inline unsigned pack_bf16(float a, float b) {
    union { float f; unsigned i; } ua, ub;
    ua.f = a; ub.f = b;
    unsigned x = (ua.i + 0x7fffu + ((ua.i >> 16) & 1u)) >> 16;
    unsigned y = (ub.i + 0x7fffu + ((ub.i >> 16) & 1u)) >> 16;
    return x | (y << 16);
}
__device__ inline unsigned short to_bf16(float a) {
    union { float f; unsigned i; } u; u.f = a;
    return (unsigned short)((u.i + 0x7fffu + ((u.i >> 16) & 1u)) >> 16);
}
// --- accumulate bf16x2 (packed uint) into two floats ----------------------
__device__ inline void acc_bf16x2(unsigned u, float& a, float& b) {
    union { unsigned i; float f; } lo, hi;
    lo.i = u << 16;
    hi.i = u & 0xffff0000u;
    a += lo.f; b += hi.f;
}

// --- fused count+place: slot = atomicAdd(cnt), XCD-partitioned by dst -----
__global__ void fill_kernel(const int* __restrict__ src, const int* __restrict__ dst,
                            int* __restrict__ cnt, int* __restrict__ adj,
                            int E, int npc) {
    int cls = blockIdx.x & 7;          // -> XCD (round-robin heuristic)
    int base = (blockIdx.x >> 3) * EDGE_CHUNK;
    int end = min(base + EDGE_CHUNK, E);
    int lo = cls * npc, hi = lo + npc;
    for (int e = base + threadIdx.x; e < end; e += blockDim.x) {
        int d = dst[e];
        if (d >= lo && d < hi) {
            int p = atomicAdd(&cnt[d], 1);
            adj[(size_t)d * CAP + p] = src[e];
        }
    }
}

// --- g(bf16) = dinv ⊙ (in @ W) via MFMA; 64 rows/block, 4 waves ----------
__global__ __launch_bounds__(256) void gemm_kernel(const float* __restrict__ in,
                                                   const float* __restrict__ W,
                                                   const int* __restrict__ cnt,
                                                   unsigned short* __restrict__ g, int n) {
    // B-fragments: 8 (s,c) combos x 64 lanes x 8 bf16 = 8 KB
    __shared__ unsigned short Wb[512 * 8];
    int t = threadIdx.x;

    // ---- stage W into B-fragment order (bf16) ----
#pragma unroll
    for (int e0 = 0; e0 < 2; e0++) {
        int e = t + e0 * 256;          // frag index 0..511
        int sc = e >> 6;               // s*4 + c
        int l  = e & 63;               // target lane
        int s = sc >> 2, c = sc & 3;
        int nn = c * 16 + (l & 15);
        int kb = s * 32 + (l >> 4) * 8;
        const float* wp = &W[(size_t)kb * 64 + nn];
        unsigned q0 = pack_bf16(wp[0 * 64], wp[1 * 64]);
        unsigned q1 = pack_bf16(wp[2 * 64], wp[3 * 64]);
        unsigned q2 = pack_bf16(wp[4 * 64], wp[5 * 64]);
        unsigned q3 = pack_bf16(wp[6 * 64], wp[7 * 64]);
        *(uint4*)&Wb[e * 8] = make_uint4(q0, q1, q2, q3);
    }

    int wv = t >> 6;
    int lane = t & 63;
    int quad = lane >> 4;
    int m16 = lane & 15;

    // ---- A fragments: row m16 of this wave's 16-row slab, k per quad ----
    int rowA = blockIdx.x * 64 + wv * 16 + m16;
    union { bf16x8 v; uint4 u; } a0, a1;
    {
        float4 f0 = make_float4(0, 0, 0, 0), f1 = f0, f2 = f0, f3 = f0;
        if (rowA < n) {
            const float* rp = &in[(size_t)rowA * 64];
            f0 = *(const float4*)&rp[quad * 8];
            f1 = *(const float4*)&rp[quad * 8 + 4];
            f2 = *(const float4*)&rp[32 + quad * 8];
            f3 = *(const float4*)&rp[32 + quad * 8 + 4];
        }
        a0.u = make_uint4(pack_bf16(f0.x, f0.y), pack_bf16(f0.z, f0.w),
                          pack_bf16(f1.x, f1.y), pack_bf16(f1.z, f1.w));
        a1.u = make_uint4(pack_bf16(f2.x, f2.y), pack_bf16(f2.z, f2.w),
                          pack_bf16(f3.x, f3.y), pack_bf16(f3.z, f3.w));
    }
    __syncthreads();

    // ---- 8 MFMAs: 4 col-tiles x 2 k-steps ----
    f32x4 acc[4];
#pragma unroll
    for (int c = 0; c < 4; c++) {
        bf16x8 b0 = *(const bf16x8*)&Wb[((size_t)(0 * 4 + c) * 64 + lane) * 8];
        bf16x8 b1 = *(const bf16x8*)&Wb[((size_t)(1 * 4 + c) * 64 + lane) * 8];
        f32x4 z = {0.f, 0.f, 0.f, 0.f};
        z = __builtin_amdgcn_mfma_f32_16x16x32_bf16(a0.v, b0, z, 0, 0, 0);
        z = __builtin_amdgcn_mfma_f32_16x16x32_bf16(a1.v, b1, z, 0, 0, 0);
        acc[c] = z;
    }

    // ---- epilogue: scale by dinv[row], store bf16 (C rows = quad*4+reg) ----
    int rowbase = blockIdx.x * 64 + wv * 16 + quad * 4;
    float dv[4];
#pragma unroll
    for (int r = 0; r < 4; r++) {
        int row = rowbase + r;
        dv[r] = (row < n) ? rsqrtf((float)(cnt[row] + 1)) : 0.f;
    }
#pragma unroll
    for (int c = 0; c < 4; c++) {
#pragma unroll
        for (int r = 0; r < 4; r++) {
            int row = rowbase + r;
            if (row < n)
                g[(size_t)row * 64 + c * 16 + m16] = to_bf16(acc[c][r] * dv[r]);
        }
    }
}

// --- aggregation (R6 form): 16 lanes/node (uint2 = 4 bf16), unroll-8 ------
// out[i] = dinv[i]*(g[i] + sum_nbr g[j]) + bias  (+relu+res for MODE 0)
template <int MODE>
__global__ __launch_bounds__(256) void agg_kernel(const unsigned short* __restrict__ g,
                                                  const int* __restrict__ cnt,
                                                  const int* __restrict__ adj,
                                                  const float* __restrict__ bias,
                                                  const float* __restrict__ res,
                                                  float* __restrict__ out, int n) {
    int t = threadIdx.x;
    int lg = t & 15;
    int i = blockIdx.x * 16 + (t >> 4);
    if (i >= n) return;
    int deg = cnt[i];
    const int* lst = adj + (size_t)i * CAP;
    const int c4 = lg * 4;
    float ax = 0.f, ay = 0.f, az = 0.f, aw = 0.f;
    {   // self loop
        uint2 v = *(const uint2*)&g[(size_t)i * 64 + c4];
        acc_bf16x2(v.x, ax, ay);
        acc_bf16x2(v.y, az, aw);
    }
    int k = 0;
    for (; k + 8 <= deg; k += 8) {
        int j0 = lst[k], j1 = lst[k + 1], j2 = lst[k + 2], j3 = lst[k + 3];
        int j4 = lst[k + 4], j5 = lst[k + 5], j6 = lst[k + 6], j7 = lst[k + 7];
        uint2 v0 = *(const uint2*)&g[(size_t)j0 * 64 + c4];
        uint2 v1 = *(const uint2*)&g[(size_t)j1 * 64 + c4];
        uint2 v2 = *(const uint2*)&g[(size_t)j2 * 64 + c4];
        uint2 v3 = *(const uint2*)&g[(size_t)j3 * 64 + c4];
        uint2 v4 = *(const uint2*)&g[(size_t)j4 * 64 + c4];
        uint2 v5 = *(const uint2*)&g[(size_t)j5 * 64 + c4];
        uint2 v6 = *(const uint2*)&g[(size_t)j6 * 64 + c4];
        uint2 v7 = *(const uint2*)&g[(size_t)j7 * 64 + c4];
        acc_bf16x2(v0.x, ax, ay); acc_bf16x2(v0.y, az, aw);
        acc_bf16x2(v1.x, ax, ay); acc_bf16x2(v1.y, az, aw);
        acc_bf16x2(v2.x, ax, ay); acc_bf16x2(v2.y, az, aw);
        acc_bf16x2(v3.x, ax, ay); acc_bf16x2(v3.y, az, aw);
        acc_bf16x2(v4.x, ax, ay); acc_bf16x2(v4.y, az, aw);
        acc_bf16x2(v5.x, ax, ay); acc_bf16x2(v5.y, az, aw);
        acc_bf16x2(v6.x, ax, ay); acc_bf16x2(v6.y, az, aw);
        acc_bf16x2(v7.x, ax, ay); acc_bf16x2(v7.y, az, aw);
    }
    if (k + 4 <= deg) {
        int j0 = lst[k], j1 = lst[k + 1], j2 = lst[k + 2], j3 = lst[k + 3];
        uint2 v0 = *(const uint2*)&g[(size_t)j0 * 64 + c4];
        uint2 v1 = *(const uint2*)&g[(size_t)j1 * 64 + c4];
        uint2 v2 = *(const uint2*)&g[(size_t)j2 * 64 + c4];
        uint2 v3 = *(const uint2*)&g[(size_t)j3 * 64 + c4];
        acc_bf16x2(v0.x, ax, ay); acc_bf16x2(v0.y, az, aw);
        acc_bf16x2(v1.x, ax, ay); acc_bf16x2(v1.y, az, aw);
        acc_bf16x2(v2.x, ax, ay); acc_bf16x2(v2.y, az, aw);
        acc_bf16x2(v3.x, ax, ay); acc_bf16x2(v3.y, az, aw);
        k += 4;
    }
    for (; k < deg; k++) {
        uint2 v = *(const uint2*)&g[(size_t)lst[k] * 64 + c4];
        acc_bf16x2(v.x, ax, ay);
        acc_bf16x2(v.y, az, aw);
    }
    float dv = rsqrtf((float)(deg + 1));
    float4 bb = *(const float4*)&bias[c4];
    float4 v;
    v.x = dv * ax + bb.x;
    v.y = dv * ay + bb.y;
    v.z = dv * az + bb.z;
    v.w = dv * aw + bb.w;
    if (MODE == 0) {
        float4 r = *(const float4*)&res[(size_t)i * 64 + c4];
        v.x = fmaxf(v.x, 0.f) + r.x;
        v.y = fmaxf(v.y, 0.f) + r.y;
        v.z = fmaxf(v.z, 0.f) + r.z;
        v.w = fmaxf(v.w, 0.f) + r.w;
    }
    *(float4*)&out[(size_t)i * 64 + c4] = v;
}

extern "C" void kernel_launch(void* const* d_in, const int* in_sizes, int n_in,
                              void* d_out, int out_size, void* d_ws, size_t ws_size,
                              hipStream_t stream) {
    const float* x  = (const float*)d_in[0];
    const int*   ei = (const int*)d_in[1];
    const float* W1 = (const float*)d_in[2];
    const float* b1 = (const float*)d_in[3];
    const float* W2 = (const float*)d_in[4];
    const float* b2 = (const float*)d_in[5];
    const float* W3 = (const float*)d_in[6];
    const float* b3 = (const float*)d_in[7];
    float* out = (float*)d_out;

    const int N = in_sizes[0] / 64;
    const int E = in_sizes[1] / 2;
    const int* src = ei;
    const int* dst = ei + E;
    const int npc = (N + 7) / 8;
    const int nEdgeChunks = (E + EDGE_CHUNK - 1) / EDGE_CHUNK;

    // workspace layout
    char* p = (char*)d_ws;
    int*            cnt = (int*)p;            p += ((N + 63) / 64) * 64 * 4;
    int*            adj = (int*)p;            p += ((size_t)N + 1) * CAP * 4;
    unsigned short* g   = (unsigned short*)p; p += (size_t)N * 64 * 2;
    float*          h   = (float*)p;          p += (size_t)N * 64 * 4;

    const int aggBlocks  = (N + 15) / 16;
    const int gemmBlocks = (N + 63) / 64;

    // --- bucket adjacency build (ws re-poisoned every call) ---
    hipMemsetAsync(cnt, 0, (size_t)N * 4, stream);
    fill_kernel<<<nEdgeChunks * 8, 256, 0, stream>>>(src, dst, cnt, adj, E, npc);

    // --- layer 1: h = relu(agg(dinv⊙(x@W1))) + x ---
    gemm_kernel<<<gemmBlocks, 256, 0, stream>>>(x, W1, cnt, g, N);
    agg_kernel<0><<<aggBlocks, 256, 0, stream>>>(g, cnt, adj, b1, x, h, N);

    // --- layer 2: h = relu(agg(dinv⊙(h@W2))) + h ---
    gemm_kernel<<<gemmBlocks, 256, 0, stream>>>(h, W2, cnt, g, N);
    agg_kernel<0><<<aggBlocks, 256, 0, stream>>>(g, cnt, adj, b2, h, h, N);

    // --- layer 3: out = agg(dinv⊙(h@W3)) ---
    gemm_kernel<<<gemmBlocks, 256, 0, stream>>>(h, W3, cnt, g, N);
    agg_kernel<1><<<aggBlocks, 256, 0, stream>>>(g, cnt, adj, b3, nullptr, out, N);
}